// Round 1
// baseline (8315.678 us; speedup 1.0000x reference)
//
#include <hip/hip_runtime.h>

#define D 128

// ---------------- norm precompute ----------------
__global__ void k_deg_init(float* deg, int n) {
  int i = blockIdx.x * blockDim.x + threadIdx.x;
  if (i < n) deg[i] = 1.0f;  // self-loop
}

__global__ void k_deg_count(const int* __restrict__ ei, float* deg, int E) {
  int e = blockIdx.x * blockDim.x + threadIdx.x;
  if (e < E) atomicAdd(&deg[ei[E + e]], 1.0f);  // dst row of edge_index
}

__global__ void k_dinv(float* deg, int n) {
  int i = blockIdx.x * blockDim.x + threadIdx.x;
  if (i < n) deg[i] = rsqrtf(deg[i]);  // deg >= 1 always (self-loop)
}

// ---------------- GEMM: C[n,128] = A[n,128] @ W[128,128] (f32, no MFMA on CDNA4) ----------------
__launch_bounds__(256)
__global__ void k_gemm(const float* __restrict__ A, const float* __restrict__ W,
                       float* __restrict__ C, int n) {
  __shared__ float Ws[D * D];    // 64 KB
  __shared__ float As[64 * D];   // 32 KB
  const int tid = threadIdx.x;
  for (int i = tid; i < D * D / 4; i += 256)
    ((float4*)Ws)[i] = ((const float4*)W)[i];
  const int row0 = blockIdx.x * 64;
  for (int i = tid; i < 64 * D / 4; i += 256) {
    int r = i >> 5;  // 32 float4 per row
    int gr = row0 + r;
    float4 v = make_float4(0.f, 0.f, 0.f, 0.f);
    if (gr < n) v = ((const float4*)A)[gr * 32 + (i & 31)];
    ((float4*)As)[i] = v;
  }
  __syncthreads();
  const int tx = tid & 31;   // col group: 4 cols
  const int ty = tid >> 5;   // row group: 8 rows
  const int c0 = tx * 4;
  const int r0 = ty * 8;
  float acc[8][4];
#pragma unroll
  for (int i = 0; i < 8; i++)
#pragma unroll
    for (int j = 0; j < 4; j++) acc[i][j] = 0.f;
  for (int k = 0; k < D; k += 4) {
    float4 w0 = *(const float4*)&Ws[(k + 0) * D + c0];
    float4 w1 = *(const float4*)&Ws[(k + 1) * D + c0];
    float4 w2 = *(const float4*)&Ws[(k + 2) * D + c0];
    float4 w3 = *(const float4*)&Ws[(k + 3) * D + c0];
#pragma unroll
    for (int i = 0; i < 8; i++) {
      float4 a = *(const float4*)&As[(r0 + i) * D + k];
      acc[i][0] += a.x * w0.x + a.y * w1.x + a.z * w2.x + a.w * w3.x;
      acc[i][1] += a.x * w0.y + a.y * w1.y + a.z * w2.y + a.w * w3.y;
      acc[i][2] += a.x * w0.z + a.y * w1.z + a.z * w2.z + a.w * w3.z;
      acc[i][3] += a.x * w0.w + a.y * w1.w + a.z * w2.w + a.w * w3.w;
    }
  }
#pragma unroll
  for (int i = 0; i < 8; i++) {
    int gr = row0 + r0 + i;
    if (gr < n)
      *(float4*)&C[gr * D + c0] = make_float4(acc[i][0], acc[i][1], acc[i][2], acc[i][3]);
  }
}

// agg = t * dinv[row]^2 (self-loop msg) + bias  -- also initializes the accumulator
__global__ void k_init_agg(const float* __restrict__ t, const float* __restrict__ dinv,
                           const float* __restrict__ b, float* __restrict__ agg, int n4) {
  int i = blockIdx.x * blockDim.x + threadIdx.x;
  if (i >= n4) return;
  int row = i >> 5;
  float di = dinv[row];
  float sc = di * di;
  float4 v = ((const float4*)t)[i];
  float4 bb = ((const float4*)b)[i & 31];
  v.x = v.x * sc + bb.x;
  v.y = v.y * sc + bb.y;
  v.z = v.z * sc + bb.z;
  v.w = v.w * sc + bb.w;
  ((float4*)agg)[i] = v;
}

// one 64-lane wave per edge; lane handles 2 consecutive floats
__launch_bounds__(256)
__global__ void k_scatter(const int* __restrict__ ei, const float* __restrict__ t,
                          const float* __restrict__ dinv, float* __restrict__ agg, int E) {
  int e = blockIdx.x * 4 + (threadIdx.x >> 6);
  if (e >= E) return;
  int lane = threadIdx.x & 63;
  int s = ei[e];
  int d = ei[E + e];
  float nrm = dinv[s] * dinv[d];
  float2 v = ((const float2*)(t + (size_t)s * D))[lane];
  float* dst = agg + (size_t)d * D + lane * 2;
  atomicAdd(dst, v.x * nrm);
  atomicAdd(dst + 1, v.y * nrm);
}

__global__ void k_relu(float* __restrict__ g, int n4) {
  int i = blockIdx.x * blockDim.x + threadIdx.x;
  if (i >= n4) return;
  float4 v = ((float4*)g)[i];
  v.x = fmaxf(v.x, 0.f); v.y = fmaxf(v.y, 0.f);
  v.z = fmaxf(v.z, 0.f); v.w = fmaxf(v.w, 0.f);
  ((float4*)g)[i] = v;
}

__global__ void k_add_relu(float* __restrict__ io, const float* __restrict__ res, int n4) {
  int i = blockIdx.x * blockDim.x + threadIdx.x;
  if (i >= n4) return;
  float4 v = ((const float4*)io)[i];
  float4 r = ((const float4*)res)[i];
  v.x = fmaxf(v.x + r.x, 0.f);
  v.y = fmaxf(v.y + r.y, 0.f);
  v.z = fmaxf(v.z + r.z, 0.f);
  v.w = fmaxf(v.w + r.w, 0.f);
  ((float4*)io)[i] = v;
}

extern "C" void kernel_launch(void* const* d_in, const int* in_sizes, int n_in,
                              void* d_out, int out_size, void* d_ws, size_t ws_size,
                              hipStream_t stream) {
  const float* x  = (const float*)d_in[0];
  const int*   ei = (const int*)d_in[1];
  const float* W0 = (const float*)d_in[2];
  const float* b0 = (const float*)d_in[3];
  const float* W1 = (const float*)d_in[4];
  const float* b1 = (const float*)d_in[5];
  const float* W2 = (const float*)d_in[6];
  const float* b2 = (const float*)d_in[7];
  float* out = (float*)d_out;

  const int N = in_sizes[0] / D;   // 100000
  const int E = in_sizes[1] / 2;   // 3200000
  const int n4 = N * (D / 4);      // float4 count per node-feature buffer

  float* ws = (float*)d_ws;
  float* dinv = ws;                              // N floats (deg, then dinv in place)
  float* t    = ws + ((N + 127) & ~127);         // N*128 (transformed features)
  float* g1   = t + (size_t)N * D;               // N*128 (h1, residual)

  dim3 b256(256);
  int gN   = (N + 255) / 256;
  int gE   = (E + 255) / 256;
  int gn4  = (n4 + 255) / 256;
  int gGem = (N + 63) / 64;
  int gSc  = (E + 3) / 4;

  // norm
  k_deg_init<<<gN, b256, 0, stream>>>(dinv, N);
  k_deg_count<<<gE, b256, 0, stream>>>(ei, dinv, E);
  k_dinv<<<gN, b256, 0, stream>>>(dinv, N);

  // layer 0: h1 = relu(Agg(x@W0) + b0)
  k_gemm<<<gGem, b256, 0, stream>>>(x, W0, t, N);
  k_init_agg<<<gn4, b256, 0, stream>>>(t, dinv, b0, g1, n4);
  k_scatter<<<gSc, b256, 0, stream>>>(ei, t, dinv, g1, E);
  k_relu<<<gn4, b256, 0, stream>>>(g1, n4);

  // layer 1: h2 = relu(Agg(h1@W1) + b1 + h1)   (accumulate in d_out)
  k_gemm<<<gGem, b256, 0, stream>>>(g1, W1, t, N);
  k_init_agg<<<gn4, b256, 0, stream>>>(t, dinv, b1, out, n4);
  k_scatter<<<gSc, b256, 0, stream>>>(ei, t, dinv, out, E);
  k_add_relu<<<gn4, b256, 0, stream>>>(out, g1, n4);

  // layer 2: out = Agg(h2@W2) + b2   (GEMM consumes d_out into t, then d_out is reused)
  k_gemm<<<gGem, b256, 0, stream>>>(out, W2, t, N);
  k_init_agg<<<gn4, b256, 0, stream>>>(t, dinv, b2, out, n4);
  k_scatter<<<gSc, b256, 0, stream>>>(ei, t, dinv, out, E);
}

// Round 2
// 1435.448 us; speedup vs baseline: 5.7931x; 5.7931x over previous
//
#include <hip/hip_runtime.h>

#define D 128

// ---------------- degree histogram ----------------
__global__ void k_zero_int(int* p, int n) {
  int i = blockIdx.x * blockDim.x + threadIdx.x;
  if (i < n) p[i] = 0;
}

__global__ void k_deg_count(const int* __restrict__ ei, int* __restrict__ deg, int E) {
  int e = blockIdx.x * blockDim.x + threadIdx.x;
  if (e < E) atomicAdd(&deg[ei[E + e]], 1);  // dst row
}

// ---------------- prefix sum (CHUNK = 2048 = 256 threads x 8) ----------------
__global__ void k_scan_part(const int* __restrict__ deg, int* __restrict__ part, int n) {
  __shared__ int sd[256];
  int base = blockIdx.x * 2048 + threadIdx.x * 8;
  int s = 0;
#pragma unroll
  for (int k = 0; k < 8; k++) {
    int idx = base + k;
    if (idx < n) s += deg[idx];
  }
  sd[threadIdx.x] = s;
  __syncthreads();
  for (int off = 128; off > 0; off >>= 1) {
    if (threadIdx.x < off) sd[threadIdx.x] += sd[threadIdx.x + off];
    __syncthreads();
  }
  if (threadIdx.x == 0) part[blockIdx.x] = sd[0];
}

__global__ void k_scan_offsets(int* __restrict__ part, int nparts,
                               int* __restrict__ rowptr, int n) {
  __shared__ int sd[256];
  int v = (threadIdx.x < nparts) ? part[threadIdx.x] : 0;
  sd[threadIdx.x] = v;
  __syncthreads();
  for (int off = 1; off < 256; off <<= 1) {
    int t = (threadIdx.x >= off) ? sd[threadIdx.x - off] : 0;
    __syncthreads();
    sd[threadIdx.x] += t;
    __syncthreads();
  }
  if (threadIdx.x < nparts) part[threadIdx.x] = sd[threadIdx.x] - v;  // exclusive
  if (threadIdx.x == 0) rowptr[n] = sd[255];                          // total = E
}

__global__ void k_scan_final(const int* __restrict__ deg, const int* __restrict__ part,
                             int* __restrict__ rowptr, int n) {
  __shared__ int sd[256];
  int base = blockIdx.x * 2048 + threadIdx.x * 8;
  int loc[8];
  int s = 0;
#pragma unroll
  for (int k = 0; k < 8; k++) {
    int idx = base + k;
    loc[k] = (idx < n) ? deg[idx] : 0;
    s += loc[k];
  }
  sd[threadIdx.x] = s;
  __syncthreads();
  for (int off = 1; off < 256; off <<= 1) {
    int t = (threadIdx.x >= off) ? sd[threadIdx.x - off] : 0;
    __syncthreads();
    sd[threadIdx.x] += t;
    __syncthreads();
  }
  int run = part[blockIdx.x] + sd[threadIdx.x] - s;  // exclusive offset
#pragma unroll
  for (int k = 0; k < 8; k++) {
    int idx = base + k;
    if (idx < n) {
      rowptr[idx] = run;
      run += loc[k];
    }
  }
}

// dinv = rsqrt(in_deg + 1 self-loop); also init cursor = rowptr
__global__ void k_dinv_cursor(const int* __restrict__ rowptr, float* __restrict__ dinv,
                              int* __restrict__ cursor, int n) {
  int i = blockIdx.x * blockDim.x + threadIdx.x;
  if (i < n) {
    int r0 = rowptr[i], r1 = rowptr[i + 1];
    dinv[i] = rsqrtf((float)(r1 - r0) + 1.0f);
    cursor[i] = r0;
  }
}

__global__ void k_csr_fill(const int* __restrict__ ei, int* __restrict__ cursor,
                           int* __restrict__ csr_src, int E) {
  int e = blockIdx.x * blockDim.x + threadIdx.x;
  if (e >= E) return;
  int s = ei[e];
  int d = ei[E + e];
  int pos = atomicAdd(&cursor[d], 1);
  csr_src[pos] = s;
}

// ---------------- GEMM: C[n,128] = A[n,128] @ W[128,128] (f32 vector ALU) ----------------
__launch_bounds__(256)
__global__ void k_gemm(const float* __restrict__ A, const float* __restrict__ W,
                       float* __restrict__ C, int n) {
  __shared__ float Ws[D * D];    // 64 KB
  __shared__ float As[64 * D];   // 32 KB
  const int tid = threadIdx.x;
  for (int i = tid; i < D * D / 4; i += 256)
    ((float4*)Ws)[i] = ((const float4*)W)[i];
  const int row0 = blockIdx.x * 64;
  for (int i = tid; i < 64 * D / 4; i += 256) {
    int r = i >> 5;
    int gr = row0 + r;
    float4 v = make_float4(0.f, 0.f, 0.f, 0.f);
    if (gr < n) v = ((const float4*)A)[gr * 32 + (i & 31)];
    ((float4*)As)[i] = v;
  }
  __syncthreads();
  const int tx = tid & 31;
  const int ty = tid >> 5;
  const int c0 = tx * 4;
  const int r0 = ty * 8;
  float acc[8][4];
#pragma unroll
  for (int i = 0; i < 8; i++)
#pragma unroll
    for (int j = 0; j < 4; j++) acc[i][j] = 0.f;
  for (int k = 0; k < D; k += 4) {
    float4 w0 = *(const float4*)&Ws[(k + 0) * D + c0];
    float4 w1 = *(const float4*)&Ws[(k + 1) * D + c0];
    float4 w2 = *(const float4*)&Ws[(k + 2) * D + c0];
    float4 w3 = *(const float4*)&Ws[(k + 3) * D + c0];
#pragma unroll
    for (int i = 0; i < 8; i++) {
      float4 a = *(const float4*)&As[(r0 + i) * D + k];
      acc[i][0] += a.x * w0.x + a.y * w1.x + a.z * w2.x + a.w * w3.x;
      acc[i][1] += a.x * w0.y + a.y * w1.y + a.z * w2.y + a.w * w3.y;
      acc[i][2] += a.x * w0.z + a.y * w1.z + a.z * w2.z + a.w * w3.z;
      acc[i][3] += a.x * w0.w + a.y * w1.w + a.z * w2.w + a.w * w3.w;
    }
  }
#pragma unroll
  for (int i = 0; i < 8; i++) {
    int gr = row0 + r0 + i;
    if (gr < n)
      *(float4*)&C[gr * D + c0] = make_float4(acc[i][0], acc[i][1], acc[i][2], acc[i][3]);
  }
}

// ---------------- pull-style aggregation, one wave per dst node ----------------
// acc = t[node]*dinv^2 + b  +  sum_{edges} dinv[s]*dinv[node] * t[s]
// MODE 0: out = relu(acc);  MODE 1: out = relu(acc + res);  MODE 2: out = acc
template <int MODE>
__launch_bounds__(256)
__global__ void k_aggregate(const int* __restrict__ rowptr, const int* __restrict__ csr_src,
                            const float* __restrict__ dinv, const float* __restrict__ t,
                            const float* __restrict__ b, const float* __restrict__ res,
                            float* __restrict__ out, int n) {
  int node = blockIdx.x * 4 + (threadIdx.x >> 6);
  if (node >= n) return;
  int lane = threadIdx.x & 63;
  int beg = rowptr[node];
  int end = rowptr[node + 1];
  float dd = dinv[node];

  float2 tv = ((const float2*)(t + (size_t)node * D))[lane];
  float2 bb = ((const float2*)b)[lane];
  float sc = dd * dd;
  float ax = tv.x * sc + bb.x;
  float ay = tv.y * sc + bb.y;

  for (int j = beg; j < end; j += 64) {
    int m = end - j;
    if (m > 64) m = 64;
    int sv = 0;
    float nv = 0.f;
    if (lane < m) {
      sv = csr_src[j + lane];
      nv = dinv[sv] * dd;
    }
    for (int k = 0; k < m; k++) {
      int s = __shfl(sv, k);
      float nrm = __shfl(nv, k);
      float2 v = ((const float2*)(t + (size_t)s * D))[lane];
      ax += v.x * nrm;
      ay += v.y * nrm;
    }
  }

  if (MODE == 1) {
    float2 rr = ((const float2*)(res + (size_t)node * D))[lane];
    ax += rr.x;
    ay += rr.y;
  }
  if (MODE == 0 || MODE == 1) {
    ax = fmaxf(ax, 0.f);
    ay = fmaxf(ay, 0.f);
  }
  ((float2*)(out + (size_t)node * D))[lane] = make_float2(ax, ay);
}

extern "C" void kernel_launch(void* const* d_in, const int* in_sizes, int n_in,
                              void* d_out, int out_size, void* d_ws, size_t ws_size,
                              hipStream_t stream) {
  const float* x  = (const float*)d_in[0];
  const int*   ei = (const int*)d_in[1];
  const float* W0 = (const float*)d_in[2];
  const float* b0 = (const float*)d_in[3];
  const float* W1 = (const float*)d_in[4];
  const float* b1 = (const float*)d_in[5];
  const float* W2 = (const float*)d_in[6];
  const float* b2 = (const float*)d_in[7];
  float* out = (float*)d_out;

  const int N = in_sizes[0] / D;   // 100000
  const int E = in_sizes[1] / 2;   // 3200000

  // workspace layout (4-byte elements, 256B-aligned chunks)
  char* wsb = (char*)d_ws;
  auto alloc = [&](size_t elems) {
    char* p = wsb;
    wsb += ((elems * 4 + 255) & ~(size_t)255);
    return p;
  };
  int*   rowptr  = (int*)alloc(N + 1);
  int*   cursor  = (int*)alloc(N);      // also used as deg histogram
  int*   part    = (int*)alloc(256);
  float* dinv    = (float*)alloc(N);
  int*   csr_src = (int*)alloc(E);
  float* t       = (float*)alloc((size_t)N * D);
  float* g1      = (float*)alloc((size_t)N * D);

  dim3 b256(256);
  int gN   = (N + 255) / 256;
  int gE   = (E + 255) / 256;
  int gGem = (N + 63) / 64;
  int gAgg = (N + 3) / 4;
  int nparts = (N + 2047) / 2048;   // 49

  // ---- CSR build (once; reused by all 3 layers) ----
  int* deg = cursor;  // reuse: deg histogram lives in cursor buffer pre-scan
  k_zero_int<<<gN, b256, 0, stream>>>(deg, N);
  k_deg_count<<<gE, b256, 0, stream>>>(ei, deg, E);
  k_scan_part<<<nparts, b256, 0, stream>>>(deg, part, N);
  k_scan_offsets<<<1, b256, 0, stream>>>(part, nparts, rowptr, N);
  k_scan_final<<<nparts, b256, 0, stream>>>(deg, part, rowptr, N);
  k_dinv_cursor<<<gN, b256, 0, stream>>>(rowptr, dinv, cursor, N);
  k_csr_fill<<<gE, b256, 0, stream>>>(ei, cursor, csr_src, E);

  // ---- layer 0: g1 = relu(Agg(x@W0) + b0) ----
  k_gemm<<<gGem, b256, 0, stream>>>(x, W0, t, N);
  k_aggregate<0><<<gAgg, b256, 0, stream>>>(rowptr, csr_src, dinv, t, b0, nullptr, g1, N);

  // ---- layer 1: out(h2) = relu(Agg(g1@W1) + b1 + g1) ----
  k_gemm<<<gGem, b256, 0, stream>>>(g1, W1, t, N);
  k_aggregate<1><<<gAgg, b256, 0, stream>>>(rowptr, csr_src, dinv, t, b1, g1, out, N);

  // ---- layer 2: out = Agg(h2@W2) + b2 ----
  k_gemm<<<gGem, b256, 0, stream>>>(out, W2, t, N);
  k_aggregate<2><<<gAgg, b256, 0, stream>>>(rowptr, csr_src, dinv, t, b2, nullptr, out, N);
}

// Round 3
// 1373.937 us; speedup vs baseline: 6.0524x; 1.0448x over previous
//
#include <hip/hip_runtime.h>

#define D 128

// ---------------- degree histogram ----------------
__global__ void k_zero_int(int* p, int n) {
  int i = blockIdx.x * blockDim.x + threadIdx.x;
  if (i < n) p[i] = 0;
}

__global__ void k_deg_count(const int* __restrict__ ei, int* __restrict__ deg, int E) {
  int e = blockIdx.x * blockDim.x + threadIdx.x;
  if (e < E) atomicAdd(&deg[ei[E + e]], 1);  // dst row
}

// ---------------- prefix sum (CHUNK = 2048 = 256 threads x 8) ----------------
__global__ void k_scan_part(const int* __restrict__ deg, int* __restrict__ part, int n) {
  __shared__ int sd[256];
  int base = blockIdx.x * 2048 + threadIdx.x * 8;
  int s = 0;
#pragma unroll
  for (int k = 0; k < 8; k++) {
    int idx = base + k;
    if (idx < n) s += deg[idx];
  }
  sd[threadIdx.x] = s;
  __syncthreads();
  for (int off = 128; off > 0; off >>= 1) {
    if (threadIdx.x < off) sd[threadIdx.x] += sd[threadIdx.x + off];
    __syncthreads();
  }
  if (threadIdx.x == 0) part[blockIdx.x] = sd[0];
}

__global__ void k_scan_offsets(int* __restrict__ part, int nparts,
                               int* __restrict__ rowptr, int n) {
  __shared__ int sd[256];
  int v = (threadIdx.x < nparts) ? part[threadIdx.x] : 0;
  sd[threadIdx.x] = v;
  __syncthreads();
  for (int off = 1; off < 256; off <<= 1) {
    int t = (threadIdx.x >= off) ? sd[threadIdx.x - off] : 0;
    __syncthreads();
    sd[threadIdx.x] += t;
    __syncthreads();
  }
  if (threadIdx.x < nparts) part[threadIdx.x] = sd[threadIdx.x] - v;  // exclusive
  if (threadIdx.x == 0) rowptr[n] = sd[255];                          // total = E
}

__global__ void k_scan_final(const int* __restrict__ deg, const int* __restrict__ part,
                             int* __restrict__ rowptr, int n) {
  __shared__ int sd[256];
  int base = blockIdx.x * 2048 + threadIdx.x * 8;
  int loc[8];
  int s = 0;
#pragma unroll
  for (int k = 0; k < 8; k++) {
    int idx = base + k;
    loc[k] = (idx < n) ? deg[idx] : 0;
    s += loc[k];
  }
  sd[threadIdx.x] = s;
  __syncthreads();
  for (int off = 1; off < 256; off <<= 1) {
    int t = (threadIdx.x >= off) ? sd[threadIdx.x - off] : 0;
    __syncthreads();
    sd[threadIdx.x] += t;
    __syncthreads();
  }
  int run = part[blockIdx.x] + sd[threadIdx.x] - s;  // exclusive offset
#pragma unroll
  for (int k = 0; k < 8; k++) {
    int idx = base + k;
    if (idx < n) {
      rowptr[idx] = run;
      run += loc[k];
    }
  }
}

// dinv = rsqrt(in_deg + 1 self-loop); also init cursor = rowptr
__global__ void k_dinv_cursor(const int* __restrict__ rowptr, float* __restrict__ dinv,
                              int* __restrict__ cursor, int n) {
  int i = blockIdx.x * blockDim.x + threadIdx.x;
  if (i < n) {
    int r0 = rowptr[i], r1 = rowptr[i + 1];
    dinv[i] = rsqrtf((float)(r1 - r0) + 1.0f);
    cursor[i] = r0;
  }
}

__global__ void k_csr_fill(const int* __restrict__ ei, int* __restrict__ cursor,
                           int* __restrict__ csr_src, int E) {
  int e = blockIdx.x * blockDim.x + threadIdx.x;
  if (e >= E) return;
  int s = ei[e];
  int d = ei[E + e];
  int pos = atomicAdd(&cursor[d], 1);
  csr_src[pos] = s;
}

// ---------------- GEMM: C[n,128] = A[n,128] @ W[128,128] (f32 vector ALU) ----------------
// 128x128 tile per block, 256 threads, 8x8 outputs/thread.
// As staged TRANSPOSED: As[k][row], stride 129 (pad) so k-loop reads are b128.
__launch_bounds__(256, 1)
__global__ void k_gemm(const float* __restrict__ A, const float* __restrict__ W,
                       float* __restrict__ C, int n) {
  __shared__ float Ws[D * D];       // 64 KB, [k][col]
  __shared__ float As[D * 129];     // 64.5 KB, [k][row] transposed, pad 129
  const int tid = threadIdx.x;
  const int row0 = blockIdx.x * 128;

  // stage W (row-major [k][col]), float4 coalesced
  for (int i = tid; i < D * D / 4; i += 256)
    ((float4*)Ws)[i] = ((const float4*)W)[i];

  // stage A transposed: thread i loads A[row][k4..k4+3] (coalesced), writes 4 scalars
  for (int i = tid; i < 128 * 32; i += 256) {
    int r = i >> 5;            // local row 0..127
    int k4 = (i & 31) << 2;    // k base
    int gr = row0 + r;
    float4 v = make_float4(0.f, 0.f, 0.f, 0.f);
    if (gr < n) v = ((const float4*)A)[(size_t)gr * 32 + (i & 31)];
    As[(k4 + 0) * 129 + r] = v.x;
    As[(k4 + 1) * 129 + r] = v.y;
    As[(k4 + 2) * 129 + r] = v.z;
    As[(k4 + 3) * 129 + r] = v.w;
  }
  __syncthreads();

  const int tx = tid & 15;    // col group
  const int ty = tid >> 4;    // row group
  const int c0 = tx * 4;      // cols c0..c0+3 and c0+64..c0+67
  const int r0 = ty * 4;      // rows r0..r0+3 and r0+64..r0+67

  float acc[8][8];
#pragma unroll
  for (int i = 0; i < 8; i++)
#pragma unroll
    for (int j = 0; j < 8; j++) acc[i][j] = 0.f;

#pragma unroll 4
  for (int k = 0; k < D; k++) {
    float4 a0 = *(const float4*)&As[k * 129 + r0];
    float4 a1 = *(const float4*)&As[k * 129 + r0 + 64];
    float4 w0 = *(const float4*)&Ws[k * D + c0];
    float4 w1 = *(const float4*)&Ws[k * D + c0 + 64];
    float av[8] = {a0.x, a0.y, a0.z, a0.w, a1.x, a1.y, a1.z, a1.w};
    float wv[8] = {w0.x, w0.y, w0.z, w0.w, w1.x, w1.y, w1.z, w1.w};
#pragma unroll
    for (int i = 0; i < 8; i++)
#pragma unroll
      for (int j = 0; j < 8; j++) acc[i][j] = fmaf(av[i], wv[j], acc[i][j]);
  }

#pragma unroll
  for (int i = 0; i < 8; i++) {
    int gr = row0 + r0 + (i & 3) + (i >> 2) * 64;
    if (gr < n) {
      *(float4*)&C[(size_t)gr * D + c0] =
          make_float4(acc[i][0], acc[i][1], acc[i][2], acc[i][3]);
      *(float4*)&C[(size_t)gr * D + c0 + 64] =
          make_float4(acc[i][4], acc[i][5], acc[i][6], acc[i][7]);
    }
  }
}

// ---------------- pull-style aggregation, one wave per dst node ----------------
// acc = t[node]*dinv^2 + b  +  sum_{edges} dinv[s]*dinv[node] * t[s]
// MODE 0: out = relu(acc);  MODE 1: out = relu(acc + res);  MODE 2: out = acc
template <int MODE>
__launch_bounds__(256)
__global__ void k_aggregate(const int* __restrict__ rowptr, const int* __restrict__ csr_src,
                            const float* __restrict__ dinv, const float* __restrict__ t,
                            const float* __restrict__ b, const float* __restrict__ res,
                            float* __restrict__ out, int n) {
  int node = blockIdx.x * 4 + (threadIdx.x >> 6);
  if (node >= n) return;
  int lane = threadIdx.x & 63;
  int beg = rowptr[node];
  int end = rowptr[node + 1];
  float dd = dinv[node];

  float2 tv = ((const float2*)(t + (size_t)node * D))[lane];
  float2 bb = ((const float2*)b)[lane];
  float sc = dd * dd;
  float ax = fmaf(tv.x, sc, bb.x);
  float ay = fmaf(tv.y, sc, bb.y);

  int j = beg;
  for (; j + 4 <= end; j += 4) {
    // uniform-address loads (HW broadcasts one request per wave)
    int s0 = csr_src[j + 0];
    int s1 = csr_src[j + 1];
    int s2 = csr_src[j + 2];
    int s3 = csr_src[j + 3];
    float n0 = dinv[s0] * dd;
    float n1 = dinv[s1] * dd;
    float n2 = dinv[s2] * dd;
    float n3 = dinv[s3] * dd;
    float2 v0 = ((const float2*)(t + (size_t)s0 * D))[lane];
    float2 v1 = ((const float2*)(t + (size_t)s1 * D))[lane];
    float2 v2 = ((const float2*)(t + (size_t)s2 * D))[lane];
    float2 v3 = ((const float2*)(t + (size_t)s3 * D))[lane];
    ax = fmaf(v0.x, n0, ax); ay = fmaf(v0.y, n0, ay);
    ax = fmaf(v1.x, n1, ax); ay = fmaf(v1.y, n1, ay);
    ax = fmaf(v2.x, n2, ax); ay = fmaf(v2.y, n2, ay);
    ax = fmaf(v3.x, n3, ax); ay = fmaf(v3.y, n3, ay);
  }
  for (; j < end; ++j) {
    int s = csr_src[j];
    float nrm = dinv[s] * dd;
    float2 v = ((const float2*)(t + (size_t)s * D))[lane];
    ax = fmaf(v.x, nrm, ax);
    ay = fmaf(v.y, nrm, ay);
  }

  if (MODE == 1) {
    float2 rr = ((const float2*)(res + (size_t)node * D))[lane];
    ax += rr.x;
    ay += rr.y;
  }
  if (MODE == 0 || MODE == 1) {
    ax = fmaxf(ax, 0.f);
    ay = fmaxf(ay, 0.f);
  }
  ((float2*)(out + (size_t)node * D))[lane] = make_float2(ax, ay);
}

extern "C" void kernel_launch(void* const* d_in, const int* in_sizes, int n_in,
                              void* d_out, int out_size, void* d_ws, size_t ws_size,
                              hipStream_t stream) {
  const float* x  = (const float*)d_in[0];
  const int*   ei = (const int*)d_in[1];
  const float* W0 = (const float*)d_in[2];
  const float* b0 = (const float*)d_in[3];
  const float* W1 = (const float*)d_in[4];
  const float* b1 = (const float*)d_in[5];
  const float* W2 = (const float*)d_in[6];
  const float* b2 = (const float*)d_in[7];
  float* out = (float*)d_out;

  const int N = in_sizes[0] / D;   // 100000
  const int E = in_sizes[1] / 2;   // 3200000

  // workspace layout (4-byte elements, 256B-aligned chunks)
  char* wsb = (char*)d_ws;
  auto alloc = [&](size_t elems) {
    char* p = wsb;
    wsb += ((elems * 4 + 255) & ~(size_t)255);
    return p;
  };
  int*   rowptr  = (int*)alloc(N + 1);
  int*   cursor  = (int*)alloc(N);      // also used as deg histogram
  int*   part    = (int*)alloc(256);
  float* dinv    = (float*)alloc(N);
  int*   csr_src = (int*)alloc(E);
  float* t       = (float*)alloc((size_t)N * D);
  float* g1      = (float*)alloc((size_t)N * D);

  dim3 b256(256);
  int gN   = (N + 255) / 256;
  int gE   = (E + 255) / 256;
  int gGem = (N + 127) / 128;
  int gAgg = (N + 3) / 4;
  int nparts = (N + 2047) / 2048;   // 49

  // ---- CSR build (once; reused by all 3 layers) ----
  int* deg = cursor;  // deg histogram lives in cursor buffer pre-scan
  k_zero_int<<<gN, b256, 0, stream>>>(deg, N);
  k_deg_count<<<gE, b256, 0, stream>>>(ei, deg, E);
  k_scan_part<<<nparts, b256, 0, stream>>>(deg, part, N);
  k_scan_offsets<<<1, b256, 0, stream>>>(part, nparts, rowptr, N);
  k_scan_final<<<nparts, b256, 0, stream>>>(deg, part, rowptr, N);
  k_dinv_cursor<<<gN, b256, 0, stream>>>(rowptr, dinv, cursor, N);
  k_csr_fill<<<gE, b256, 0, stream>>>(ei, cursor, csr_src, E);

  // ---- layer 0: g1 = relu(Agg(x@W0) + b0) ----
  k_gemm<<<gGem, b256, 0, stream>>>(x, W0, t, N);
  k_aggregate<0><<<gAgg, b256, 0, stream>>>(rowptr, csr_src, dinv, t, b0, nullptr, g1, N);

  // ---- layer 1: out(h2) = relu(Agg(g1@W1) + b1 + g1) ----
  k_gemm<<<gGem, b256, 0, stream>>>(g1, W1, t, N);
  k_aggregate<1><<<gAgg, b256, 0, stream>>>(rowptr, csr_src, dinv, t, b1, g1, out, N);

  // ---- layer 2: out = Agg(h2@W2) + b2 ----
  k_gemm<<<gGem, b256, 0, stream>>>(out, W2, t, N);
  k_aggregate<2><<<gAgg, b256, 0, stream>>>(rowptr, csr_src, dinv, t, b2, nullptr, out, N);
}

// Round 4
// 1355.406 us; speedup vs baseline: 6.1352x; 1.0137x over previous
//
#include <hip/hip_runtime.h>

#define D 128

// ---------------- degree histogram ----------------
__global__ void k_zero_int(int* p, int n) {
  int i = blockIdx.x * blockDim.x + threadIdx.x;
  if (i < n) p[i] = 0;
}

__global__ void k_deg_count(const int* __restrict__ ei, int* __restrict__ deg, int E) {
  int e = blockIdx.x * blockDim.x + threadIdx.x;
  if (e < E) atomicAdd(&deg[ei[E + e]], 1);  // dst row
}

// ---------------- prefix sum (CHUNK = 2048 = 256 threads x 8) ----------------
__global__ void k_scan_part(const int* __restrict__ deg, int* __restrict__ part, int n) {
  __shared__ int sd[256];
  int base = blockIdx.x * 2048 + threadIdx.x * 8;
  int s = 0;
#pragma unroll
  for (int k = 0; k < 8; k++) {
    int idx = base + k;
    if (idx < n) s += deg[idx];
  }
  sd[threadIdx.x] = s;
  __syncthreads();
  for (int off = 128; off > 0; off >>= 1) {
    if (threadIdx.x < off) sd[threadIdx.x] += sd[threadIdx.x + off];
    __syncthreads();
  }
  if (threadIdx.x == 0) part[blockIdx.x] = sd[0];
}

__global__ void k_scan_offsets(int* __restrict__ part, int nparts,
                               int* __restrict__ rowptr, int n) {
  __shared__ int sd[256];
  int v = (threadIdx.x < nparts) ? part[threadIdx.x] : 0;
  sd[threadIdx.x] = v;
  __syncthreads();
  for (int off = 1; off < 256; off <<= 1) {
    int t = (threadIdx.x >= off) ? sd[threadIdx.x - off] : 0;
    __syncthreads();
    sd[threadIdx.x] += t;
    __syncthreads();
  }
  if (threadIdx.x < nparts) part[threadIdx.x] = sd[threadIdx.x] - v;  // exclusive
  if (threadIdx.x == 0) rowptr[n] = sd[255];                          // total = E
}

__global__ void k_scan_final(const int* __restrict__ deg, const int* __restrict__ part,
                             int* __restrict__ rowptr, int n) {
  __shared__ int sd[256];
  int base = blockIdx.x * 2048 + threadIdx.x * 8;
  int loc[8];
  int s = 0;
#pragma unroll
  for (int k = 0; k < 8; k++) {
    int idx = base + k;
    loc[k] = (idx < n) ? deg[idx] : 0;
    s += loc[k];
  }
  sd[threadIdx.x] = s;
  __syncthreads();
  for (int off = 1; off < 256; off <<= 1) {
    int t = (threadIdx.x >= off) ? sd[threadIdx.x - off] : 0;
    __syncthreads();
    sd[threadIdx.x] += t;
    __syncthreads();
  }
  int run = part[blockIdx.x] + sd[threadIdx.x] - s;  // exclusive offset
#pragma unroll
  for (int k = 0; k < 8; k++) {
    int idx = base + k;
    if (idx < n) {
      rowptr[idx] = run;
      run += loc[k];
    }
  }
}

// dinv = rsqrt(in_deg + 1 self-loop); also init cursor = rowptr
__global__ void k_dinv_cursor(const int* __restrict__ rowptr, float* __restrict__ dinv,
                              int* __restrict__ cursor, int n) {
  int i = blockIdx.x * blockDim.x + threadIdx.x;
  if (i < n) {
    int r0 = rowptr[i], r1 = rowptr[i + 1];
    dinv[i] = rsqrtf((float)(r1 - r0) + 1.0f);
    cursor[i] = r0;
  }
}

// bucketed fill: only edges whose dst is in [lo,hi) are placed this pass.
// packed entry = src | (float_bits(norm) << 32); write region ~E/8*8B = L2-resident.
__global__ void k_csr_fill_b(const int* __restrict__ ei, const float* __restrict__ dinv,
                             int* __restrict__ cursor,
                             unsigned long long* __restrict__ packed,
                             int E, int lo, int hi) {
  int e = blockIdx.x * blockDim.x + threadIdx.x;
  if (e >= E) return;
  int d = __builtin_nontemporal_load(&ei[E + e]);
  if (d < lo || d >= hi) return;
  int s = __builtin_nontemporal_load(&ei[e]);
  float nrm = dinv[s] * dinv[d];
  int pos = atomicAdd(&cursor[d], 1);
  packed[pos] = (unsigned long long)(unsigned)s |
                ((unsigned long long)__float_as_uint(nrm) << 32);
}

// ---------------- GEMM: C[n,128] = A[n,128] @ W[128,128] (f32 vector ALU) ----------------
__launch_bounds__(256, 1)
__global__ void k_gemm(const float* __restrict__ A, const float* __restrict__ W,
                       float* __restrict__ C, int n) {
  __shared__ float Ws[D * D];       // 64 KB, [k][col]
  __shared__ float As[D * 129];     // 64.5 KB, [k][row] transposed, pad 129
  const int tid = threadIdx.x;
  const int row0 = blockIdx.x * 128;

  for (int i = tid; i < D * D / 4; i += 256)
    ((float4*)Ws)[i] = ((const float4*)W)[i];

  for (int i = tid; i < 128 * 32; i += 256) {
    int r = i >> 5;
    int k4 = (i & 31) << 2;
    int gr = row0 + r;
    float4 v = make_float4(0.f, 0.f, 0.f, 0.f);
    if (gr < n) v = ((const float4*)A)[(size_t)gr * 32 + (i & 31)];
    As[(k4 + 0) * 129 + r] = v.x;
    As[(k4 + 1) * 129 + r] = v.y;
    As[(k4 + 2) * 129 + r] = v.z;
    As[(k4 + 3) * 129 + r] = v.w;
  }
  __syncthreads();

  const int tx = tid & 15;
  const int ty = tid >> 4;
  const int c0 = tx * 4;
  const int r0 = ty * 4;

  float acc[8][8];
#pragma unroll
  for (int i = 0; i < 8; i++)
#pragma unroll
    for (int j = 0; j < 8; j++) acc[i][j] = 0.f;

#pragma unroll 4
  for (int k = 0; k < D; k++) {
    float4 a0 = *(const float4*)&As[k * 129 + r0];
    float4 a1 = *(const float4*)&As[k * 129 + r0 + 64];
    float4 w0 = *(const float4*)&Ws[k * D + c0];
    float4 w1 = *(const float4*)&Ws[k * D + c0 + 64];
    float av[8] = {a0.x, a0.y, a0.z, a0.w, a1.x, a1.y, a1.z, a1.w};
    float wv[8] = {w0.x, w0.y, w0.z, w0.w, w1.x, w1.y, w1.z, w1.w};
#pragma unroll
    for (int i = 0; i < 8; i++)
#pragma unroll
      for (int j = 0; j < 8; j++) acc[i][j] = fmaf(av[i], wv[j], acc[i][j]);
  }

#pragma unroll
  for (int i = 0; i < 8; i++) {
    int gr = row0 + r0 + (i & 3) + (i >> 2) * 64;
    if (gr < n) {
      *(float4*)&C[(size_t)gr * D + c0] =
          make_float4(acc[i][0], acc[i][1], acc[i][2], acc[i][3]);
      *(float4*)&C[(size_t)gr * D + c0 + 64] =
          make_float4(acc[i][4], acc[i][5], acc[i][6], acc[i][7]);
    }
  }
}

// ---------------- pull-style aggregation ----------------
// 2 nodes per wave: lanes 0-31 node A, lanes 32-63 node B; each lane holds float4 (32x16B=512B row).
// packed stream gives (src, norm) -> no dependent dinv gather.
// MODE 0: out = relu(acc);  MODE 1: out = relu(acc + res);  MODE 2: out = acc
template <int MODE>
__launch_bounds__(256)
__global__ void k_aggregate(const int* __restrict__ rowptr,
                            const unsigned long long* __restrict__ packed,
                            const float* __restrict__ dinv, const float* __restrict__ t,
                            const float* __restrict__ b, const float* __restrict__ res,
                            float* __restrict__ out, int n) {
  const int wid = threadIdx.x >> 6;
  const int half = (threadIdx.x >> 5) & 1;
  const int l32 = threadIdx.x & 31;
  int node = blockIdx.x * 8 + wid * 2 + half;
  if (node >= n) return;

  int beg = rowptr[node];
  int end = rowptr[node + 1];
  float dd = dinv[node];

  const float4* t4 = (const float4*)t;
  float4 tv = t4[(size_t)node * 32 + l32];
  float4 bb = ((const float4*)b)[l32];
  float sc = dd * dd;
  float4 acc;
  acc.x = fmaf(tv.x, sc, bb.x);
  acc.y = fmaf(tv.y, sc, bb.y);
  acc.z = fmaf(tv.z, sc, bb.z);
  acc.w = fmaf(tv.w, sc, bb.w);

  int j = beg;
  for (; j + 4 <= end; j += 4) {
    unsigned long long q0 = __builtin_nontemporal_load(&packed[j + 0]);
    unsigned long long q1 = __builtin_nontemporal_load(&packed[j + 1]);
    unsigned long long q2 = __builtin_nontemporal_load(&packed[j + 2]);
    unsigned long long q3 = __builtin_nontemporal_load(&packed[j + 3]);
    float4 v0 = t4[(size_t)(unsigned)(q0 & 0xffffffffu) * 32 + l32];
    float4 v1 = t4[(size_t)(unsigned)(q1 & 0xffffffffu) * 32 + l32];
    float4 v2 = t4[(size_t)(unsigned)(q2 & 0xffffffffu) * 32 + l32];
    float4 v3 = t4[(size_t)(unsigned)(q3 & 0xffffffffu) * 32 + l32];
    float n0 = __uint_as_float((unsigned)(q0 >> 32));
    float n1 = __uint_as_float((unsigned)(q1 >> 32));
    float n2 = __uint_as_float((unsigned)(q2 >> 32));
    float n3 = __uint_as_float((unsigned)(q3 >> 32));
    acc.x = fmaf(v0.x, n0, acc.x); acc.y = fmaf(v0.y, n0, acc.y);
    acc.z = fmaf(v0.z, n0, acc.z); acc.w = fmaf(v0.w, n0, acc.w);
    acc.x = fmaf(v1.x, n1, acc.x); acc.y = fmaf(v1.y, n1, acc.y);
    acc.z = fmaf(v1.z, n1, acc.z); acc.w = fmaf(v1.w, n1, acc.w);
    acc.x = fmaf(v2.x, n2, acc.x); acc.y = fmaf(v2.y, n2, acc.y);
    acc.z = fmaf(v2.z, n2, acc.z); acc.w = fmaf(v2.w, n2, acc.w);
    acc.x = fmaf(v3.x, n3, acc.x); acc.y = fmaf(v3.y, n3, acc.y);
    acc.z = fmaf(v3.z, n3, acc.z); acc.w = fmaf(v3.w, n3, acc.w);
  }
  for (; j < end; ++j) {
    unsigned long long q = __builtin_nontemporal_load(&packed[j]);
    float4 v = t4[(size_t)(unsigned)(q & 0xffffffffu) * 32 + l32];
    float nrm = __uint_as_float((unsigned)(q >> 32));
    acc.x = fmaf(v.x, nrm, acc.x);
    acc.y = fmaf(v.y, nrm, acc.y);
    acc.z = fmaf(v.z, nrm, acc.z);
    acc.w = fmaf(v.w, nrm, acc.w);
  }

  if (MODE == 1) {
    float4 rr = ((const float4*)res)[(size_t)node * 32 + l32];
    acc.x += rr.x; acc.y += rr.y; acc.z += rr.z; acc.w += rr.w;
  }
  if (MODE == 0 || MODE == 1) {
    acc.x = fmaxf(acc.x, 0.f);
    acc.y = fmaxf(acc.y, 0.f);
    acc.z = fmaxf(acc.z, 0.f);
    acc.w = fmaxf(acc.w, 0.f);
  }
  ((float4*)out)[(size_t)node * 32 + l32] = acc;
}

extern "C" void kernel_launch(void* const* d_in, const int* in_sizes, int n_in,
                              void* d_out, int out_size, void* d_ws, size_t ws_size,
                              hipStream_t stream) {
  const float* x  = (const float*)d_in[0];
  const int*   ei = (const int*)d_in[1];
  const float* W0 = (const float*)d_in[2];
  const float* b0 = (const float*)d_in[3];
  const float* W1 = (const float*)d_in[4];
  const float* b1 = (const float*)d_in[5];
  const float* W2 = (const float*)d_in[6];
  const float* b2 = (const float*)d_in[7];
  float* out = (float*)d_out;

  const int N = in_sizes[0] / D;   // 100000
  const int E = in_sizes[1] / 2;   // 3200000

  // workspace layout (4-byte elements, 256B-aligned chunks)
  char* wsb = (char*)d_ws;
  auto alloc = [&](size_t elems) {
    char* p = wsb;
    wsb += ((elems * 4 + 255) & ~(size_t)255);
    return p;
  };
  int*   rowptr  = (int*)alloc(N + 1);
  int*   cursor  = (int*)alloc(N);      // also used as deg histogram
  int*   part    = (int*)alloc(256);
  float* dinv    = (float*)alloc(N);
  unsigned long long* packed = (unsigned long long*)alloc(2 * (size_t)E);
  float* t       = (float*)alloc((size_t)N * D);
  float* g1      = (float*)alloc((size_t)N * D);

  dim3 b256(256);
  int gN   = (N + 255) / 256;
  int gE   = (E + 255) / 256;
  int gGem = (N + 127) / 128;
  int gAgg = (N + 7) / 8;
  int nparts = (N + 2047) / 2048;   // 49

  // ---- CSR build (once; reused by all 3 layers) ----
  int* deg = cursor;  // deg histogram lives in cursor buffer pre-scan
  k_zero_int<<<gN, b256, 0, stream>>>(deg, N);
  k_deg_count<<<gE, b256, 0, stream>>>(ei, deg, E);
  k_scan_part<<<nparts, b256, 0, stream>>>(deg, part, N);
  k_scan_offsets<<<1, b256, 0, stream>>>(part, nparts, rowptr, N);
  k_scan_final<<<nparts, b256, 0, stream>>>(deg, part, rowptr, N);
  k_dinv_cursor<<<gN, b256, 0, stream>>>(rowptr, dinv, cursor, N);
  const int NB = 8;
  int bsz = (N + NB - 1) / NB;
  for (int b = 0; b < NB; b++) {
    int lo = b * bsz;
    int hi = lo + bsz;
    if (hi > N) hi = N;
    k_csr_fill_b<<<gE, b256, 0, stream>>>(ei, dinv, cursor, packed, E, lo, hi);
  }

  // ---- layer 0: g1 = relu(Agg(x@W0) + b0) ----
  k_gemm<<<gGem, b256, 0, stream>>>(x, W0, t, N);
  k_aggregate<0><<<gAgg, b256, 0, stream>>>(rowptr, packed, dinv, t, b0, nullptr, g1, N);

  // ---- layer 1: out(h2) = relu(Agg(g1@W1) + b1 + g1) ----
  k_gemm<<<gGem, b256, 0, stream>>>(g1, W1, t, N);
  k_aggregate<1><<<gAgg, b256, 0, stream>>>(rowptr, packed, dinv, t, b1, g1, out, N);

  // ---- layer 2: out = Agg(h2@W2) + b2 ----
  k_gemm<<<gGem, b256, 0, stream>>>(out, W2, t, N);
  k_aggregate<2><<<gAgg, b256, 0, stream>>>(rowptr, packed, dinv, t, b2, nullptr, out, N);
}